// Round 7
// baseline (873.322 us; speedup 1.0000x reference)
//
#include <hip/hip_runtime.h>
#include <stdint.h>

// Multi_LSTMs: bidirectional 4-head LSTM, BS=8 NT=128 CH=1024 H=512 G=2048.
//   prep1 (pack x, cast Wih, bias) -> m97-style MFMA GEMM (128x128 tile,
//   global_load_lds) -> prep2 (cast Whh, poison-fill state)
//   -> persistent recurrence: 8 groups (dir,head) x 16 WGs.
// R1: NO agent-scope fences/acquire in step loop (buffer_wbl2/inv sc1 storm).
// R2: no same-address RMW barrier (line-lock serialization).
// R4: data-is-flag: poll state words vs bf16-NaN poison (h never NaN).
// R5/R6 FAILED (hang): s_getreg XCC_ID colocation check was untrustworthy ->
//   false-positive "fast" cross-XCD L2 exchange can deadlock.
// R7: trustless hybrid: producers DUAL-publish state (plain store -> local L2
//   AND relaxed agent sc1 store -> LLC); consumers poll sc0 (L2) a bounded
//   number of times, then permanently fall back to the R4-proven sc1 poll.
//   Correct under ANY workgroup->XCD mapping; fast when groups colocate.

typedef __attribute__((ext_vector_type(8))) short short8;
typedef __attribute__((ext_vector_type(4))) float floatx4;
typedef __attribute__((ext_vector_type(4))) unsigned uintx4;
typedef unsigned long long ull;

#define POISON 0x7FC07FC07FC07FC0ull  // 4 x bf16 NaN
#define P32 0x7FC07FC0u

#define GLOAD_LDS16(g, l)                                        \
  __builtin_amdgcn_global_load_lds(                              \
      (const __attribute__((address_space(1))) void*)(g),        \
      (__attribute__((address_space(3))) void*)(l), 16, 0, 0)

__device__ __forceinline__ unsigned short f2bf(float f) {
  unsigned u = __float_as_uint(f);
  u = (u + 0x7fffu + ((u >> 16) & 1u)) >> 16;  // RNE
  return (unsigned short)u;
}
__device__ __forceinline__ float sigm(float x) { return 1.0f / (1.0f + __expf(-x)); }
__device__ __forceinline__ float tanh_f(float x) {
  float ax = fabsf(x);
  float e = __expf(-2.0f * ax);
  float t = (1.0f - e) / (1.0f + e);
  return x < 0.0f ? -t : t;
}

__device__ __forceinline__ void cast4(const float* __restrict__ src,
                                      unsigned short* __restrict__ dst, int i) {
  float4 v = ((const float4*)src)[i];
  ushort4 o;
  o.x = f2bf(v.x); o.y = f2bf(v.y); o.z = f2bf(v.z); o.w = f2bf(v.w);
  ((ushort4*)dst)[i] = o;
}

// prep1: pack x (4096 blk) | cast Wih_f (8192) | cast Wih_b (8192) | bias (64)
__global__ __launch_bounds__(256) void prep1_k(
    const float* __restrict__ x, const float* __restrict__ WihF,
    const float* __restrict__ WihB, const float* __restrict__ bihF,
    const float* __restrict__ bhhF, const float* __restrict__ bihB,
    const float* __restrict__ bhhB, unsigned short* __restrict__ Xp,
    unsigned short* __restrict__ Wihb, float* __restrict__ bias) {
  int blk = blockIdx.x, tid = threadIdx.x;
  if (blk < 4096) {  // x[8][128][1024][4] f32 -> Xp[4][1024][1024] bf16, m=t*8+b
    int g = blk * 256 + tid;
    int m = g >> 10, c = g & 1023;
    int t = m >> 3, b = m & 7;
    float4 v = *(const float4*)(x + ((size_t)((b * 128 + t) * 1024 + c)) * 4);
    Xp[g]           = f2bf(v.x);
    Xp[1048576 + g] = f2bf(v.y);
    Xp[2097152 + g] = f2bf(v.z);
    Xp[3145728 + g] = f2bf(v.w);
  } else if (blk < 12288) {
    cast4(WihF, Wihb, (blk - 4096) * 256 + tid);
  } else if (blk < 20480) {
    cast4(WihB, Wihb + 8388608, (blk - 12288) * 256 + tid);
  } else {
    int i = (blk - 20480) * 256 + tid;  // < 16384
    int dk = i >> 11, g = i & 2047, kk = dk & 3;
    const float* a = (dk < 4) ? bihF : bihB;
    const float* b = (dk < 4) ? bhhF : bhhB;
    bias[i] = a[kk * 2048 + g] + b[kk * 2048 + g];
  }
}

// prep2 (post-GEMM overlays): cast Whh_f (4096) | Whh_b (4096) | poison (4096)
__global__ __launch_bounds__(256) void prep2_k(
    const float* __restrict__ WhhF, const float* __restrict__ WhhB,
    unsigned short* __restrict__ Whhb, ull* __restrict__ stateS) {
  int blk = blockIdx.x, tid = threadIdx.x;
  if (blk < 4096) {
    cast4(WhhF, Whhb, blk * 256 + tid);
  } else if (blk < 8192) {
    cast4(WhhB, Whhb + 4194304, (blk - 4096) * 256 + tid);
  } else {
    stateS[(size_t)(blk - 8192) * 256 + tid] = POISON;
  }
}

// ih[dk][m][g] = sum_c Xp[kh][m][c] * Wb[dk][g][c] + bias[dk][g]
// m97 structure: 128x128 tile, BK=32, global_load_lds(16B), 4 waves 2x2,
// each wave 64x64 = 4x4 accs of 16x16x32.
__global__ __launch_bounds__(256) void gemm_ih_k(
    const unsigned short* __restrict__ Xp, const unsigned short* __restrict__ Wb,
    const float* __restrict__ bias, float* __restrict__ ih) {
  const int mt = blockIdx.x, ntl = blockIdx.y, dk = blockIdx.z;
  const int kh = dk & 3;
  const int tid = threadIdx.x;
  const int L = tid & 63, w = tid >> 6;
  const int wm = w & 1, wn = w >> 1;
  const int quad = L >> 4, lo = L & 15;

  __shared__ unsigned short As[128 * 32];  // 8 KB, no pad (glds contiguity)
  __shared__ unsigned short Bs[128 * 32];

  const unsigned short* Ab = Xp + (size_t)kh * 1048576 + (size_t)mt * 128 * 1024;
  const unsigned short* Bb = Wb + (size_t)dk * 2097152 + (size_t)ntl * 128 * 1024;

  floatx4 acc[4][4] = {};

  for (int kc = 0; kc < 32; ++kc) {
#pragma unroll
    for (int q = 0; q < 2; ++q) {
      int c = q * 256 + w * 64 + L;       // 16B chunk id, 0..511
      int ldsb = (q * 256 + w * 64) * 8;  // wave-uniform base (shorts)
      GLOAD_LDS16(Ab + (size_t)(c >> 2) * 1024 + kc * 32 + (c & 3) * 8, As + ldsb);
      GLOAD_LDS16(Bb + (size_t)(c >> 2) * 1024 + kc * 32 + (c & 3) * 8, Bs + ldsb);
    }
    __syncthreads();  // implicit vmcnt(0): LDS tiles ready
    short8 af[4], bf[4];
#pragma unroll
    for (int mi = 0; mi < 4; ++mi)
      af[mi] = *(const short8*)(As + (wm * 64 + mi * 16 + lo) * 32 + quad * 8);
#pragma unroll
    for (int ni = 0; ni < 4; ++ni)
      bf[ni] = *(const short8*)(Bs + (wn * 64 + ni * 16 + lo) * 32 + quad * 8);
#pragma unroll
    for (int mi = 0; mi < 4; ++mi)
#pragma unroll
      for (int ni = 0; ni < 4; ++ni)
        acc[mi][ni] = __builtin_amdgcn_mfma_f32_16x16x32_bf16(af[mi], bf[ni], acc[mi][ni], 0, 0, 0);
    __syncthreads();  // LDS reads done before next stage
  }

#pragma unroll
  for (int mi = 0; mi < 4; ++mi)
#pragma unroll
    for (int ni = 0; ni < 4; ++ni) {
      int g = ntl * 128 + wn * 64 + ni * 16 + lo;
      float bv = bias[dk * 2048 + g];
#pragma unroll
      for (int r = 0; r < 4; ++r) {
        int m = mt * 128 + wm * 64 + mi * 16 + quad * 4 + r;  // row=(L>>4)*4+r, col=L&15
        ih[((size_t)dk * 1024 + m) * 2048 + g] = acc[mi][ni][r] + bv;
      }
    }
}

// Persistent recurrence. grid=128: group = blockIdx&7, wg = blockIdx>>3 owns
// h-cols [wg*32, wg*32+32). Wave w = gate (i,f,g,o), 2 N-tiles each.
// stateS[grp][s][8][128] ull: slot s = h input for step s; poison-polled.
__global__ __launch_bounds__(256) void lstm_rec_k(
    const float* __restrict__ ih, const unsigned short* __restrict__ whh,
    float* __restrict__ out, ull* __restrict__ stateS) {
  const int tid = threadIdx.x;
  const int L = tid & 63;
  const int w = tid >> 6;
  const int grp = blockIdx.x & 7;
  const int d = grp >> 2, kh = grp & 3;
  const int wg = blockIdx.x >> 3;
  const int j0 = wg * 32;
  const int quad = L >> 4, lo = L & 15;

  __shared__ unsigned short h_lds[16 * 520];  // rows 8..15 stay zero (M-pad)
  __shared__ float gbuf[4][8][32];            // [gate][b][jj]

  for (int i = tid; i < 16 * 520; i += 256) h_lds[i] = 0;

  // Whh slice -> register B-frags: wave w, gate rows g = w*512 + j0 + ni*16 + lo
  short8 bfrag[2][16];
#pragma unroll
  for (int ni = 0; ni < 2; ++ni) {
    const unsigned short* wb =
        whh + ((size_t)grp * 2048 + (size_t)(w * 512 + j0 + ni * 16 + lo)) * 512 + quad * 8;
#pragma unroll
    for (int kk = 0; kk < 16; ++kk) bfrag[ni][kk] = *(const short8*)(wb + kk * 32);
  }

  const int pb = tid >> 5, pjj = tid & 31;  // pointwise cell (b, jj)
  float creg = 0.0f;

  // prefetch ih gates for s=0
  float ihv[2][4];
  {
    int t0 = d ? 127 : 0;
#pragma unroll
    for (int ni = 0; ni < 2; ++ni) {
      const float* ihp =
          ih + ((size_t)grp * 1024 + (size_t)t0 * 8) * 2048 + (w * 512 + j0 + ni * 16 + lo);
#pragma unroll
      for (int r = 0; r < 4; ++r) {
        int b = quad * 4 + r;
        ihv[ni][r] = (b < 8) ? ihp[(size_t)b * 2048] : 0.0f;
      }
    }
  }

  const int srow = tid >> 5;         // batch row 0..7
  const int scol = (tid & 31) * 16;  // h-col base within row (elements)

  for (int s = 0; s < 128; ++s) {
    const int t = d ? (127 - s) : s;

    if (s) {  // stage h_prev: poll slot s until this thread's producers wrote it
      const ull* src = stateS + ((size_t)grp * 128 + s) * 1024 + tid * 4;
      unsigned short* dl = h_lds + srow * 520 + scol;
      // Phase 1 (bounded): sc0 loads — L1-bypass, served by this XCD's L2.
      // Succeeds iff producer is same-XCD (plain store landed in shared L2).
      uintx4 A, B;
      bool ok = false;
      for (int it = 0; it < 24; ++it) {
        asm volatile(
            "global_load_dwordx4 %0, %2, off sc0\n\t"
            "global_load_dwordx4 %1, %2, off offset:16 sc0\n\t"
            "s_waitcnt vmcnt(0)"
            : "=&v"(A), "=&v"(B)
            : "v"(src)
            : "memory");
        if (!(A[0] == P32 || A[1] == P32 || A[2] == P32 || A[3] == P32 ||
              B[0] == P32 || B[1] == P32 || B[2] == P32 || B[3] == P32)) {
          ok = true;
          break;
        }
      }
      if (ok) {
        *(uintx4*)(dl) = A;
        *(uintx4*)(dl + 8) = B;
      } else {
        // Phase 2 (unbounded, guaranteed): sc1 loads vs producer's sc1 store
        // — the R4-proven LLC path. Terminates under any WG->XCD mapping.
        ull v0, v1, v2, v3;
        do {
          v0 = __hip_atomic_load(src + 0, __ATOMIC_RELAXED, __HIP_MEMORY_SCOPE_AGENT);
          v1 = __hip_atomic_load(src + 1, __ATOMIC_RELAXED, __HIP_MEMORY_SCOPE_AGENT);
          v2 = __hip_atomic_load(src + 2, __ATOMIC_RELAXED, __HIP_MEMORY_SCOPE_AGENT);
          v3 = __hip_atomic_load(src + 3, __ATOMIC_RELAXED, __HIP_MEMORY_SCOPE_AGENT);
        } while (v0 == POISON || v1 == POISON || v2 == POISON || v3 == POISON);
        *(ull*)(dl + 0) = v0;
        *(ull*)(dl + 4) = v1;
        *(ull*)(dl + 8) = v2;
        *(ull*)(dl + 12) = v3;
      }
    }
    __syncthreads();

    floatx4 acc[2] = {};
    {  // A[m][k]: m = L&15 (batch, rows 8..15 zero), k = kk*32 + quad*8 + j
      const unsigned short* ar = h_lds + lo * 520 + quad * 8;
#pragma unroll
      for (int kk = 0; kk < 16; ++kk) {
        short8 a = *(const short8*)(ar + kk * 32);
#pragma unroll
        for (int ni = 0; ni < 2; ++ni)
          acc[ni] = __builtin_amdgcn_mfma_f32_16x16x32_bf16(a, bfrag[ni][kk], acc[ni], 0, 0, 0);
      }
    }
#pragma unroll
    for (int ni = 0; ni < 2; ++ni)
#pragma unroll
      for (int r = 0; r < 4; ++r) {
        int b = quad * 4 + r;
        if (b < 8) gbuf[w][b][ni * 16 + lo] = acc[ni][r] + ihv[ni][r];
      }

    if (s < 127) {  // prefetch ih for s+1 (flies during pointwise + next poll)
      int tn = d ? (126 - s) : (s + 1);
#pragma unroll
      for (int ni = 0; ni < 2; ++ni) {
        const float* ihp =
            ih + ((size_t)grp * 1024 + (size_t)tn * 8) * 2048 + (w * 512 + j0 + ni * 16 + lo);
#pragma unroll
        for (int r = 0; r < 4; ++r) {
          int b = quad * 4 + r;
          ihv[ni][r] = (b < 8) ? ihp[(size_t)b * 2048] : 0.0f;
        }
      }
    }
    __syncthreads();

    // pointwise LSTM cell: one (b, jj) per thread
    {
      float ig = gbuf[0][pb][pjj], fg = gbuf[1][pb][pjj];
      float gg = gbuf[2][pb][pjj], og = gbuf[3][pb][pjj];
      float cn = sigm(fg) * creg + sigm(ig) * tanh_f(gg);
      creg = cn;
      float h = sigm(og) * tanh_f(cn);

      if (s < 127) {  // publish h into slot s+1: shfl-pack 4 lanes -> 8B store
        unsigned hs = f2bf(h);
        int base = L & ~3;
        unsigned v0 = __shfl(hs, base + 0);
        unsigned v1 = __shfl(hs, base + 1);
        unsigned v2 = __shfl(hs, base + 2);
        unsigned v3 = __shfl(hs, base + 3);
        if ((L & 3) == 0) {
          ull wv = (ull)v0 | ((ull)v1 << 16) | ((ull)v2 << 32) | ((ull)v3 << 48);
          ull* dst = stateS + ((size_t)grp * 128 + (s + 1)) * 1024 + pb * 128 + ((j0 + pjj) >> 2);
          // Dual-publish (same value, same address — any order is correct):
          *(volatile ull*)dst = wv;  // plain: write-through L1 -> local L2
          __hip_atomic_store(dst, wv, __ATOMIC_RELAXED,
                             __HIP_MEMORY_SCOPE_AGENT);  // sc1: -> LLC
        }
      }
      out[(((size_t)pb * 128 + t) * 1024 + d * 512 + j0 + pjj) * 4 + kh] = h;
    }
  }
}

extern "C" void kernel_launch(void* const* d_in, const int* in_sizes, int n_in,
                              void* d_out, int out_size, void* d_ws, size_t ws_size,
                              hipStream_t stream) {
  (void)in_sizes; (void)n_in; (void)out_size; (void)ws_size;
  const float* x     = (const float*)d_in[0];
  const float* Wih_f = (const float*)d_in[1];
  const float* Whh_f = (const float*)d_in[2];
  const float* bih_f = (const float*)d_in[3];
  const float* bhh_f = (const float*)d_in[4];
  const float* Wih_b = (const float*)d_in[5];
  const float* Whh_b = (const float*)d_in[6];
  const float* bih_b = (const float*)d_in[7];
  const float* bhh_b = (const float*)d_in[8];
  float* out = (float*)d_out;
  char* ws = (char*)d_ws;

  float* bias          = (float*)(ws + (256u << 10));           // 64 KB
  float* ihg           = (float*)(ws + (1ull << 20));           // 64 MB fp32 ih gates
  unsigned short* Xp   = (unsigned short*)(ws + (65ull << 20)); // 8 MB
  unsigned short* Wihb = (unsigned short*)(ws + (73ull << 20)); // 32 MB (ends 105 MB)
  unsigned short* Whhb = (unsigned short*)(ws + (65ull << 20)); // 16 MB (post-GEMM overlay)
  ull* stateS          = (ull*)(ws + (81ull << 20));            // 8 MB (post-GEMM overlay)

  prep1_k<<<20544, 256, 0, stream>>>(x, Wih_f, Wih_b, bih_f, bhh_f, bih_b, bhh_b,
                                     Xp, Wihb, bias);
  gemm_ih_k<<<dim3(8, 16, 8), 256, 0, stream>>>(Xp, Wihb, bias, ihg);
  prep2_k<<<12288, 256, 0, stream>>>(Whh_f, Whh_b, Whhb, stateS);
  lstm_rec_k<<<128, 256, 0, stream>>>(ihg, Whhb, out, stateS);
}